// Round 7
// baseline (461.106 us; speedup 1.0000x reference)
//
#include <hip/hip_runtime.h>
#include <math.h>

#define Tn 64
#define Bn 128
#define MUc 0.1f
#define REGc 1e-6f

// ---- dynamic LDS layout (float offsets), one batch per 64-thread block ----
#define OG    0        // G dbuf [2][9216]
#define OQb   18432    // Q dbuf [2][576]
#define OFb   19584    // F dbuf [2][384]
#define OWb   20352    // W dbuf [2][192]
#define Oqv   20736    // q dbuf [2][64] (padded)
#define Ocv   20864    // c dbuf [2][64]
#define Osv   20992    // s dbuf [2][64]
#define OFT   21120    // F^T [24][20]
#define OVFc  21600    // VFc[j][m] = (VF)[m][j], [24][20]
#define OWT   22080    // W^T [24][12]
#define OWS   22368    // (sc*W)^T [24][12]
#define OQh   22656    // Qh [24][28]
#define OVp   23328    // V carry [16][20]
#define Ovls  23648    // v carry [16]
#define Oqh2  23664    // qh [24]
#define Oscl  23688    // s/c [8]
#define Ow2   23696    // s - r/c [8]
#define OK2   23704    // per t (stride 200): KT[n<16][a<8] at n*12, kt at 192
#define SMEMF 36504    // 146016 bytes
// forward overlay in dead G region
#define OMs   0        // [16][20]
#define Odx   336      // [65][16]
#define OFr   1376     // [4][384]

#define AS1C(p) ((const __attribute__((address_space(1))) void*)(p))
#define AS3(p)  ((__attribute__((address_space(3))) void*)(p))
#define GLD16(gp, lp) __builtin_amdgcn_global_load_lds(AS1C(gp), AS3(lp), 16, 0, 0)
#define GLD4(gp, lp)  __builtin_amdgcn_global_load_lds(AS1C(gp), AS3(lp), 4, 0, 0)
#define VMW0() do { asm volatile("s_waitcnt vmcnt(0)" ::: "memory"); \
                    __builtin_amdgcn_sched_barrier(0); } while (0)
#define VMW9() do { asm volatile("s_waitcnt vmcnt(9)" ::: "memory"); \
                    __builtin_amdgcn_sched_barrier(0); } while (0)
// LDS phase fence: drain DS queue + pin compiler scheduling (rule #18).
#define LF()   do { asm volatile("s_waitcnt lgkmcnt(0)" ::: "memory"); \
                    __builtin_amdgcn_sched_barrier(0); } while (0)

__global__ __launch_bounds__(64, 1) void ipddp_kernel(
    const float* __restrict__ Qg, const float* __restrict__ qg,
    const float* __restrict__ Fg, const float* __restrict__ Gg,
    const float* __restrict__ Wg, const float* __restrict__ cg,
    const float* __restrict__ sg, const float* __restrict__ VTg,
    const float* __restrict__ vTg, const float* __restrict__ x0g,
    const float* __restrict__ xnomg, const float* __restrict__ unomg,
    float* __restrict__ outg)
{
  extern __shared__ float sm[];
  const int b  = blockIdx.x;
  const int ln = threadIdx.x;   // single wave

  auto STAGE = [&](int tsrc, int nx) {
    const size_t pb = (size_t)(tsrc * Bn + b);
    const float* gq = Gg + pb * 9216;
    float* gd = sm + OG + nx * 9216;
#pragma unroll
    for (int ci = 0; ci < 36; ++ci)
      GLD16(gq + ci * 256 + ln * 4, gd + ci * 256);
    GLD16(Qg + pb * 576 + ln * 4,       sm + OQb + nx * 576);
    GLD16(Qg + pb * 576 + 256 + ln * 4, sm + OQb + nx * 576 + 256);
    GLD4 (Qg + pb * 576 + 512 + ln,     sm + OQb + nx * 576 + 512);
    GLD16(Fg + pb * 384 + ln * 4,       sm + OFb + nx * 384);
    GLD4 (Fg + pb * 384 + 256 + ln,     sm + OFb + nx * 384 + 256);
    GLD4 (Fg + pb * 384 + 320 + ln,     sm + OFb + nx * 384 + 320);
    GLD4 (Wg + pb * 192 + ln,           sm + OWb + nx * 192);
    GLD4 (Wg + pb * 192 + 64 + ln,      sm + OWb + nx * 192 + 64);
    GLD4 (Wg + pb * 192 + 128 + ln,     sm + OWb + nx * 192 + 128);
    if (ln < 24) GLD4(qg + pb * 24 + ln, sm + Oqv + nx * 64);
    if (ln < 8)  GLD4(cg + pb * 8 + ln,  sm + Ocv + nx * 64);
    if (ln < 8)  GLD4(sg + pb * 8 + ln,  sm + Osv + nx * 64);
  };

  // build FT / WT / WS / scl / w2 for buffer nx (call only after VMW0)
  auto PREP = [&](int nx) {
    if (ln < 8) {
      const float cc = sm[Ocv + nx * 64 + ln], ss = sm[Osv + nx * 64 + ln];
      const float rr = fmaf(ss, cc, MUc);
      sm[Oscl + ln] = ss / cc;
      sm[Ow2 + ln]  = ss - rr / cc;
    }
    LF();   // scl visible to all lanes
#pragma unroll
    for (int e = 0; e < 3; ++e) {
      const int src = e * 64 + ln;
      const int c = src / 24, i2 = src - c * 24;
      const float w = sm[OWb + nx * 192 + src];
      sm[OWT + i2 * 12 + c] = w;
      sm[OWS + i2 * 12 + c] = w * sm[Oscl + c];
    }
#pragma unroll
    for (int e = 0; e < 6; ++e) {
      const int src = e * 64 + ln;
      const int n = src / 24, d = src - n * 24;
      sm[OFT + d * 20 + n] = sm[OFb + nx * 384 + src];
    }
  };

  // ---------------- prologue ----------------
  STAGE(Tn - 1, 1);
  {
    const int n = ln >> 2, m0 = (ln & 3) * 4;
    const float4 v4 = *(const float4*)(VTg + (size_t)b * 256 + ln * 4);
    *(float4*)(sm + OVp + n * 20 + m0) = v4;
  }
  if (ln < 16) sm[Ovls + ln] = vTg[(size_t)b * 16 + ln];
  VMW0();
  PREP(1);
  LF();

  // ---------------- backward scan (single wave, fenced phases) ----------------
#pragma unroll 1
  for (int t = Tn - 1; t >= 0; --t) {
    const int P = t & 1, nx = P ^ 1;
    const float* Gb = sm + OG + P * 9216;
    const float* Qb = sm + OQb + P * 576;

    if (t > 0) STAGE(t - 1, nx);

    // v carry to registers (Ovls fenced at iteration end)
    float vreg[16];
#pragma unroll
    for (int n = 0; n < 16; ++n) vreg[n] = sm[Ovls + n];

    // VFc[j][m] = sum_k V[m][k] * F[k][j]
#pragma unroll
    for (int e = 0; e < 6; ++e) {
      const int idx = e * 64 + ln;
      const int j = idx >> 4, m = idx & 15;
      float a = 0.f;
#pragma unroll
      for (int r = 0; r < 4; ++r) {
        const float4 vv = ((const float4*)(sm + OVp + m * 20))[r];
        const float4 ff = ((const float4*)(sm + OFT + j * 20))[r];
        a = fmaf(vv.x, ff.x, fmaf(vv.y, ff.y, fmaf(vv.z, ff.z, fmaf(vv.w, ff.w, a))));
      }
      sm[OVFc + j * 20 + m] = a;
    }
    LF();   // VFc visible

    // ---- Qh full 24x24: pass A (512 elems) ----
#pragma unroll
    for (int e = 0; e < 2; ++e) {
      const int base = e * 256 + ln * 4;
      float4 q4 = *(const float4*)(Qb + base);
      float accr[4] = {q4.x, q4.y, q4.z, q4.w};
#pragma unroll
      for (int n = 0; n < 16; ++n) {
        const float4 g = *(const float4*)(Gb + n * 576 + base);
        const float vn = vreg[n];
        accr[0] = fmaf(vn, g.x, accr[0]); accr[1] = fmaf(vn, g.y, accr[1]);
        accr[2] = fmaf(vn, g.z, accr[2]); accr[3] = fmaf(vn, g.w, accr[3]);
      }
#pragma unroll
      for (int r = 0; r < 4; ++r) {
        const int idx = base + r, i = idx / 24, j = idx - i * 24;
        float a = accr[r];
#pragma unroll
        for (int rr = 0; rr < 4; ++rr) {
          const float4 x = ((const float4*)(sm + OFT + i * 20))[rr];
          const float4 y = ((const float4*)(sm + OVFc + j * 20))[rr];
          a = fmaf(x.x, y.x, fmaf(x.y, y.y, fmaf(x.z, y.z, fmaf(x.w, y.w, a))));
        }
        {
          const float4 x0 = ((const float4*)(sm + OWT + i * 12))[0];
          const float4 x1 = ((const float4*)(sm + OWT + i * 12))[1];
          const float4 y0 = ((const float4*)(sm + OWS + j * 12))[0];
          const float4 y1 = ((const float4*)(sm + OWS + j * 12))[1];
          a = fmaf(-x0.x, y0.x, a); a = fmaf(-x0.y, y0.y, a);
          a = fmaf(-x0.z, y0.z, a); a = fmaf(-x0.w, y0.w, a);
          a = fmaf(-x1.x, y1.x, a); a = fmaf(-x1.y, y1.y, a);
          a = fmaf(-x1.z, y1.z, a); a = fmaf(-x1.w, y1.w, a);
        }
        sm[OQh + i * 28 + j] = a;
      }
    }
    // ---- pass B (last 64 elems) ----
    {
      const int idx = 512 + ln, i = idx / 24, j = idx - i * 24;
      float a = Qb[idx];
#pragma unroll
      for (int n = 0; n < 16; ++n) a = fmaf(vreg[n], Gb[n * 576 + idx], a);
#pragma unroll
      for (int rr = 0; rr < 4; ++rr) {
        const float4 x = ((const float4*)(sm + OFT + i * 20))[rr];
        const float4 y = ((const float4*)(sm + OVFc + j * 20))[rr];
        a = fmaf(x.x, y.x, fmaf(x.y, y.y, fmaf(x.z, y.z, fmaf(x.w, y.w, a))));
      }
      {
        const float4 x0 = ((const float4*)(sm + OWT + i * 12))[0];
        const float4 x1 = ((const float4*)(sm + OWT + i * 12))[1];
        const float4 y0 = ((const float4*)(sm + OWS + j * 12))[0];
        const float4 y1 = ((const float4*)(sm + OWS + j * 12))[1];
        a = fmaf(-x0.x, y0.x, a); a = fmaf(-x0.y, y0.y, a);
        a = fmaf(-x0.z, y0.z, a); a = fmaf(-x0.w, y0.w, a);
        a = fmaf(-x1.x, y1.x, a); a = fmaf(-x1.y, y1.y, a);
        a = fmaf(-x1.z, y1.z, a); a = fmaf(-x1.w, y1.w, a);
      }
      sm[OQh + i * 28 + j] = a;
    }

    // qh[i] = q[i] + F^T v + W^T w2   (lanes 0..23)
    if (ln < 24) {
      float a = sm[Oqv + P * 64 + ln];
#pragma unroll
      for (int rr = 0; rr < 4; ++rr) {
        const float4 x = ((const float4*)(sm + OFT + ln * 20))[rr];
        a = fmaf(x.x, vreg[4 * rr + 0], a); a = fmaf(x.y, vreg[4 * rr + 1], a);
        a = fmaf(x.z, vreg[4 * rr + 2], a); a = fmaf(x.w, vreg[4 * rr + 3], a);
      }
#pragma unroll
      for (int c = 0; c < 8; ++c) a = fmaf(sm[OWT + ln * 12 + c], sm[Ow2 + c], a);
      sm[Oqh2 + ln] = a;
    }
    LF();   // Qh + qh visible

    // ---- Gauss-Jordan (no pivot, Quu strongly PD), lanes 0..24 ----
    {
      float colv[8];
      const int cl = (ln < 8) ? (16 + ln) : ((ln < 24) ? (ln - 8) : 0);
#pragma unroll
      for (int a = 0; a < 8; ++a) colv[a] = 0.f;
      if (ln < 24) {
#pragma unroll
        for (int a = 0; a < 8; ++a) colv[a] = sm[OQh + (16 + a) * 28 + cl];
        if (ln < 8) colv[ln] += REGc;
      } else if (ln == 24) {
#pragma unroll
        for (int a = 0; a < 8; ++a) colv[a] = sm[Oqh2 + 16 + a];
      }
#pragma unroll
      for (int k = 0; k < 8; ++k) {
        const float pk = __shfl(colv[k], k);
        const float inv = 1.0f / pk;
        colv[k] *= inv;
#pragma unroll
        for (int a2 = 0; a2 < 8; ++a2) {
          if (a2 == k) continue;
          const float m = __shfl(colv[a2], k);
          colv[a2] = fmaf(-m, colv[k], colv[a2]);
        }
      }
      float* kbase = sm + OK2 + t * 200;
      if (ln >= 8 && ln < 24) {
        float4 w0, w1;
        w0.x = -colv[0]; w0.y = -colv[1]; w0.z = -colv[2]; w0.w = -colv[3];
        w1.x = -colv[4]; w1.y = -colv[5]; w1.z = -colv[6]; w1.w = -colv[7];
        ((float4*)(kbase + (ln - 8) * 12))[0] = w0;
        ((float4*)(kbase + (ln - 8) * 12))[1] = w1;
      } else if (ln == 24) {
        float4 w0, w1;
        w0.x = -colv[0]; w0.y = -colv[1]; w0.z = -colv[2]; w0.w = -colv[3];
        w1.x = -colv[4]; w1.y = -colv[5]; w1.z = -colv[6]; w1.w = -colv[7];
        ((float4*)(kbase + 192))[0] = w0;
        ((float4*)(kbase + 192))[1] = w1;
      }
      const float kt0 = -__shfl(colv[0], 24), kt1 = -__shfl(colv[1], 24);
      const float kt2 = -__shfl(colv[2], 24), kt3 = -__shfl(colv[3], 24);
      const float kt4 = -__shfl(colv[4], 24), kt5 = -__shfl(colv[5], 24);
      const float kt6 = -__shfl(colv[6], 24), kt7 = -__shfl(colv[7], 24);
      if (ln < 16) {
        float a = sm[Oqh2 + ln];
        const float4 qa  = ((const float4*)(sm + OQh + ln * 28 + 16))[0];
        const float4 qb2 = ((const float4*)(sm + OQh + ln * 28 + 16))[1];
        a = fmaf(qa.x, kt0, a); a = fmaf(qa.y, kt1, a);
        a = fmaf(qa.z, kt2, a); a = fmaf(qa.w, kt3, a);
        a = fmaf(qb2.x, kt4, a); a = fmaf(qb2.y, kt5, a);
        a = fmaf(qb2.z, kt6, a); a = fmaf(qb2.w, kt7, a);
        sm[Ovls + ln] = a;
      }
    }
    LF();   // K, kt, v_new visible

    // ---- V' = Qxx + Qxu*K (Schur), 4 consecutive elems per lane ----
    {
      const int n = ln >> 2, m0 = (ln & 3) * 4;
      const float* kb = sm + OK2 + t * 200;
      const float4 qa  = ((const float4*)(sm + OQh + n * 28 + 16))[0];
      const float4 qb2 = ((const float4*)(sm + OQh + n * 28 + 16))[1];
      const float4 q0 = *(const float4*)(sm + OQh + n * 28 + m0);
      float accA[4] = {q0.x, q0.y, q0.z, q0.w};
#pragma unroll
      for (int r = 0; r < 4; ++r) {
        const float4 k0 = ((const float4*)(kb + (m0 + r) * 12))[0];
        const float4 k1 = ((const float4*)(kb + (m0 + r) * 12))[1];
        float s2 = accA[r];
        s2 = fmaf(qa.x, k0.x, s2); s2 = fmaf(qa.y, k0.y, s2);
        s2 = fmaf(qa.z, k0.z, s2); s2 = fmaf(qa.w, k0.w, s2);
        s2 = fmaf(qb2.x, k1.x, s2); s2 = fmaf(qb2.y, k1.y, s2);
        s2 = fmaf(qb2.z, k1.z, s2); s2 = fmaf(qb2.w, k1.w, s2);
        accA[r] = s2;
      }
      float4 wv4; wv4.x = accA[0]; wv4.y = accA[1]; wv4.z = accA[2]; wv4.w = accA[3];
      *(float4*)(sm + OVp + n * 20 + m0) = wv4;
    }

    if (t > 0) { VMW0(); PREP(nx); }
    LF();   // OVp + next-step FT/WT/WS/scl visible
  }

  // ---------------- forward rollout ----------------
  auto FSTG = [&](int t2) {
    const size_t pb = (size_t)(t2 * Bn + b);
    const int sl = t2 & 3;
    GLD16(Fg + pb * 384 + ln * 4,     sm + OFr + sl * 384);
    GLD4 (Fg + pb * 384 + 256 + ln,   sm + OFr + sl * 384 + 256);
    GLD4 (Fg + pb * 384 + 320 + ln,   sm + OFr + sl * 384 + 320);
  };
  if (ln < 16) sm[Odx + ln] = x0g[(size_t)b * 16 + ln] - xnomg[(size_t)b * 16 + ln];
  FSTG(0); FSTG(1); FSTG(2); FSTG(3);
  LF();   // dx0 visible

#pragma unroll 1
  for (int t = 0; t < Tn; ++t) {
    VMW9();
    const float* fr0 = sm + OFr + (t & 3) * 384;
    const float* kb = sm + OK2 + t * 200;
    // M = fx + fu*K : 4 consecutive j per lane
    {
      const int i = ln >> 2, j0 = (ln & 3) * 4;
      const float* fr = fr0 + i * 24;
      const float4 fu0 = ((const float4*)(fr + 16))[0];
      const float4 fu1 = ((const float4*)(fr + 16))[1];
      const float4 m4 = *(const float4*)(fr + j0);
      float mr[4] = {m4.x, m4.y, m4.z, m4.w};
#pragma unroll
      for (int r = 0; r < 4; ++r) {
        const float4 k0 = ((const float4*)(kb + (j0 + r) * 12))[0];
        const float4 k1 = ((const float4*)(kb + (j0 + r) * 12))[1];
        float s2 = mr[r];
        s2 = fmaf(fu0.x, k0.x, s2); s2 = fmaf(fu0.y, k0.y, s2);
        s2 = fmaf(fu0.z, k0.z, s2); s2 = fmaf(fu0.w, k0.w, s2);
        s2 = fmaf(fu1.x, k1.x, s2); s2 = fmaf(fu1.y, k1.y, s2);
        s2 = fmaf(fu1.z, k1.z, s2); s2 = fmaf(fu1.w, k1.w, s2);
        mr[r] = s2;
      }
      float4 wv4; wv4.x = mr[0]; wv4.y = mr[1]; wv4.z = mr[2]; wv4.w = mr[3];
      *(float4*)(sm + OMs + i * 20 + j0) = wv4;
    }
    LF();   // M visible
    // dx' = b + M dx  (lanes 0..15)
    if (ln < 16) {
      const float* fr2 = fr0 + ln * 24;
      const float4 a0 = ((const float4*)(fr2 + 16))[0];
      const float4 a1 = ((const float4*)(fr2 + 16))[1];
      const float4 kt0 = ((const float4*)(kb + 192))[0];
      const float4 kt1 = ((const float4*)(kb + 192))[1];
      float a = 0.f;
      a = fmaf(a0.x, kt0.x, a); a = fmaf(a0.y, kt0.y, a);
      a = fmaf(a0.z, kt0.z, a); a = fmaf(a0.w, kt0.w, a);
      a = fmaf(a1.x, kt1.x, a); a = fmaf(a1.y, kt1.y, a);
      a = fmaf(a1.z, kt1.z, a); a = fmaf(a1.w, kt1.w, a);
#pragma unroll
      for (int k2 = 0; k2 < 16; ++k2)
        a = fmaf(sm[OMs + ln * 20 + k2], sm[Odx + t * 16 + k2], a);
      sm[Odx + (t + 1) * 16 + ln] = a;
    }
    LF();   // dx visible
    if (t + 4 < Tn) FSTG(t + 4);
  }

  // du_t = K_t dx_t + k_t, all t in parallel
#pragma unroll
  for (int e = 0; e < 8; ++e) {
    const int idx = e * 64 + ln;
    const int tt = idx >> 3, m = idx & 7;
    const float* kb = sm + OK2 + tt * 200;
    float a = kb[192 + m];
#pragma unroll
    for (int n = 0; n < 16; ++n) a = fmaf(kb[n * 12 + m], sm[Odx + tt * 16 + n], a);
    const size_t o = (size_t)(tt * Bn + b) * 8 + m;
    outg[o] = unomg[o] + a;
  }
}

extern "C" void kernel_launch(void* const* d_in, const int* in_sizes, int n_in,
                              void* d_out, int out_size, void* d_ws, size_t ws_size,
                              hipStream_t stream) {
  (void)in_sizes; (void)n_in; (void)out_size; (void)d_ws; (void)ws_size;
  const float* Qg    = (const float*)d_in[0];
  const float* qg    = (const float*)d_in[1];
  const float* Fg    = (const float*)d_in[2];
  const float* Gg    = (const float*)d_in[3];
  const float* Wg    = (const float*)d_in[4];
  const float* cg    = (const float*)d_in[5];
  const float* sg    = (const float*)d_in[6];
  const float* VTg   = (const float*)d_in[7];
  const float* vTg   = (const float*)d_in[8];
  const float* x0g   = (const float*)d_in[9];
  const float* xnomg = (const float*)d_in[10];
  const float* unomg = (const float*)d_in[11];
  float* outg = (float*)d_out;

  (void)hipFuncSetAttribute((const void*)ipddp_kernel,
                            hipFuncAttributeMaxDynamicSharedMemorySize,
                            SMEMF * 4);
  ipddp_kernel<<<dim3(Bn), dim3(64), SMEMF * 4, stream>>>(
      Qg, qg, Fg, Gg, Wg, cg, sg, VTg, vTg, x0g, xnomg, unomg, outg);
}

// Round 10
// 248.348 us; speedup vs baseline: 1.8567x; 1.8567x over previous
//
#include <hip/hip_runtime.h>
#include <math.h>

#define Tn 64
#define Bn 128
#define MUc 0.1f
#define REGc 1e-6f

// ---- dynamic LDS layout (float offsets) ----
// G and Q are SYMMETRIC: stage packed upper triangles only (300 elems / 24x24).
#define OGp   0        // G tri dbuf [2][16][300]
#define OQp   9600     // Q tri dbuf [2][304]
#define OFb   10208    // F dbuf [2][384]
#define OWb   10976    // W dbuf [2][192]
#define Oqv   11360    // q dbuf [2][32]
#define Ocv   11424    // c dbuf [2][8]
#define Osv   11440    // s dbuf [2][8]
#define OFT   11456    // F^T [24][20]
#define OVFc  11936    // VFc[j][m] = (VF)[m][j], [24][20]
#define OWT   12416    // W^T [24][12]
#define OWS   12704    // (sc*W)^T [24][12]
#define OQh   12992    // Qh [24][28]
#define OVp   13664    // V carry [16][20]
#define Ovls  13984    // v carry [16]
#define Oqh2  14000    // qh [24]
#define Ow2   14024    // s - r/c [8]
#define OK2   14032    // per t (stride 200): K[a][n] at n*12+a, kt at 192
#define SMEMF 26832    // 107328 bytes
// forward-pass overlay (inside dead G region)
#define OMs   0        // [2][272]
#define Obs   544      // [2][16]
#define Odx   576      // [65][16]
#define OFr   1616     // [4][384]

#define AS1C(p) ((const __attribute__((address_space(1))) void*)(p))
#define AS3(p)  ((__attribute__((address_space(3))) void*)(p))
#define GLD4(gp, lp)  __builtin_amdgcn_global_load_lds(AS1C(gp), AS3(lp), 4, 0, 0)
#define SB0() __builtin_amdgcn_sched_barrier(0)
#define VMW0() do { asm volatile("s_waitcnt vmcnt(0)" ::: "memory"); SB0(); } while (0)
#define BARRIER() do { asm volatile("s_waitcnt lgkmcnt(0)" ::: "memory"); \
  __builtin_amdgcn_s_barrier(); asm volatile("" ::: "memory"); } while (0)

// wave broadcast from compile-time-constant lane: SALU, no LDS pipe
__device__ __forceinline__ float rdl(float x, int l) {
  return __int_as_float(__builtin_amdgcn_readlane(__float_as_int(x), l));
}

__global__ __launch_bounds__(576, 1) void ipddp_kernel(
    const float* __restrict__ Qg, const float* __restrict__ qg,
    const float* __restrict__ Fg, const float* __restrict__ Gg,
    const float* __restrict__ Wg, const float* __restrict__ cg,
    const float* __restrict__ sg, const float* __restrict__ VTg,
    const float* __restrict__ vTg, const float* __restrict__ x0g,
    const float* __restrict__ xnomg, const float* __restrict__ unomg,
    float* __restrict__ outg)
{
  extern __shared__ float sm[];
  const int b   = blockIdx.x;
  const int tid = threadIdx.x;
  const int wv  = tid >> 6;
  const int ln  = tid & 63;

  // triangle map: threads 0..299 own upper-tri element (ti,tj), ti<=tj
  int ti = 0, tj = 0;
  if (tid < 300) { int idx = tid, r = 0; while (idx >= 24 - r) { idx -= 24 - r; ++r; } ti = r; tj = r + idx; }
  const int trip = ti * 24 + tj;

  // DMA one timestep's inputs into parity buffer nx.
  // G/Q: per-lane global gather -> linear packed LDS (guide m173 pattern).
  auto STAGE = [&](int tsrc, int nx) {
    const size_t pb = (size_t)(tsrc * Bn + b);
    if (tid < 300) {
      const float* gp = Gg + pb * 9216 + trip;
      float* dstb = sm + OGp + nx * 4800 + wv * 64;   // wave-uniform base
#pragma unroll
      for (int n = 0; n < 16; ++n)
        GLD4(gp + n * 576, dstb + n * 300);
      GLD4(Qg + pb * 576 + trip, sm + OQp + nx * 304 + wv * 64);
    }
    if (wv >= 1 && wv <= 6) {
      GLD4(Fg + pb * 384 + (wv - 1) * 64 + ln, sm + OFb + nx * 384 + (wv - 1) * 64);
    } else if (wv == 7) {
      GLD4(Wg + pb * 192 + ln,       sm + OWb + nx * 192);
      GLD4(Wg + pb * 192 + 64 + ln,  sm + OWb + nx * 192 + 64);
      GLD4(Wg + pb * 192 + 128 + ln, sm + OWb + nx * 192 + 128);
    } else if (wv == 8) {
      if (ln < 24) GLD4(qg + pb * 24 + ln, sm + Oqv + nx * 32);
      if (ln < 8)  GLD4(cg + pb * 8 + ln,  sm + Ocv + nx * 8);
      if (ln < 8)  GLD4(sg + pb * 8 + ln,  sm + Osv + nx * 8);
    }
  };

  // one backward step (consume parity P=t&1, stage t-1 into nx)
  auto STEP = [&](int t) {
    const int P = t & 1, nx = P ^ 1;
    const int tp = (t > 0) ? (t - 1) : 0;

    STAGE(tp, nx);

    // ---- P1: VFc[j][m] = dot(V_m, FT_j); qh on wave 6 ----
    if (tid < 384) {
      const int j = tid >> 4, m = tid & 15;
      float a = 0.f;
#pragma unroll
      for (int r = 0; r < 4; ++r) {
        const float4 vv = ((const float4*)(sm + OVp + m * 20))[r];
        const float4 ff = ((const float4*)(sm + OFT + j * 20))[r];
        a = fmaf(vv.x, ff.x, fmaf(vv.y, ff.y, fmaf(vv.z, ff.z, fmaf(vv.w, ff.w, a))));
      }
      sm[OVFc + j * 20 + m] = a;
    } else if (tid < 408) {
      const int i = tid - 384;
      float a = sm[Oqv + P * 32 + i];
#pragma unroll
      for (int r = 0; r < 4; ++r) {
        const float4 x = ((const float4*)(sm + OFT + i * 20))[r];
        const float4 y = ((const float4*)(sm + Ovls))[r];
        a = fmaf(x.x, y.x, fmaf(x.y, y.y, fmaf(x.z, y.z, fmaf(x.w, y.w, a))));
      }
#pragma unroll
      for (int c = 0; c < 8; ++c) a = fmaf(sm[OWT + i * 12 + c], sm[Ow2 + c], a);
      sm[Oqh2 + i] = a;
    }
    // pre-B1: full drain (simple, spill-immune; G had a full step to arrive)
    VMW0();
    BARRIER();   // B1

    // ---- P2: Qh triangle from packed symmetric G/Q + FVF + W terms ----
    if (tid < 300) {
      const float4 v0 = ((const float4*)(sm + Ovls))[0];
      const float4 v1 = ((const float4*)(sm + Ovls))[1];
      const float4 v2 = ((const float4*)(sm + Ovls))[2];
      const float4 v3 = ((const float4*)(sm + Ovls))[3];
      const float* gpk = sm + OGp + P * 4800 + tid;   // [n][tid] at gpk[n*300]
      float acc = sm[OQp + P * 304 + tid];
      acc = fmaf(v0.x, gpk[0],      acc); acc = fmaf(v0.y, gpk[300],  acc);
      acc = fmaf(v0.z, gpk[600],    acc); acc = fmaf(v0.w, gpk[900],  acc);
      acc = fmaf(v1.x, gpk[1200],   acc); acc = fmaf(v1.y, gpk[1500], acc);
      acc = fmaf(v1.z, gpk[1800],   acc); acc = fmaf(v1.w, gpk[2100], acc);
      acc = fmaf(v2.x, gpk[2400],   acc); acc = fmaf(v2.y, gpk[2700], acc);
      acc = fmaf(v2.z, gpk[3000],   acc); acc = fmaf(v2.w, gpk[3300], acc);
      acc = fmaf(v3.x, gpk[3600],   acc); acc = fmaf(v3.y, gpk[3900], acc);
      acc = fmaf(v3.z, gpk[4200],   acc); acc = fmaf(v3.w, gpk[4500], acc);
#pragma unroll
      for (int r = 0; r < 4; ++r) {
        const float4 x = ((const float4*)(sm + OFT + ti * 20))[r];
        const float4 y = ((const float4*)(sm + OVFc + tj * 20))[r];
        acc = fmaf(x.x, y.x, fmaf(x.y, y.y, fmaf(x.z, y.z, fmaf(x.w, y.w, acc))));
      }
      {
        const float4 x0 = ((const float4*)(sm + OWT + ti * 12))[0];
        const float4 x1 = ((const float4*)(sm + OWT + ti * 12))[1];
        const float4 y0 = ((const float4*)(sm + OWS + tj * 12))[0];
        const float4 y1 = ((const float4*)(sm + OWS + tj * 12))[1];
        acc = fmaf(-x0.x, y0.x, acc); acc = fmaf(-x0.y, y0.y, acc);
        acc = fmaf(-x0.z, y0.z, acc); acc = fmaf(-x0.w, y0.w, acc);
        acc = fmaf(-x1.x, y1.x, acc); acc = fmaf(-x1.y, y1.y, acc);
        acc = fmaf(-x1.z, y1.z, acc); acc = fmaf(-x1.w, y1.w, acc);
      }
      sm[OQh + ti * 28 + tj] = acc;
      sm[OQh + tj * 28 + ti] = acc;
    }
    BARRIER();   // B2

    // ---- P3: wave0 Gauss-Jordan (readlane broadcasts); others stage t-1 prep ----
    if (wv == 0) {
      float colv[8];
      const int cl = (ln < 8) ? (16 + ln) : ((ln < 24) ? (ln - 8) : 0);
#pragma unroll
      for (int a = 0; a < 8; ++a) colv[a] = 0.f;
      if (ln < 24) {
#pragma unroll
        for (int a = 0; a < 8; ++a) colv[a] = sm[OQh + (16 + a) * 28 + cl];
        if (ln < 8) colv[ln] += REGc;
      } else if (ln == 24) {
#pragma unroll
        for (int a = 0; a < 8; ++a) colv[a] = sm[Oqh2 + 16 + a];
      }
#pragma unroll
      for (int k = 0; k < 8; ++k) {
        const float pk = rdl(colv[k], k);
        const float inv = 1.0f / pk;
        colv[k] *= inv;
#pragma unroll
        for (int a2 = 0; a2 < 8; ++a2) {
          if (a2 == k) continue;
          const float m = rdl(colv[a2], k);
          colv[a2] = fmaf(-m, colv[k], colv[a2]);
        }
      }
      float* kbase = sm + OK2 + t * 200;
      if (ln >= 8 && ln < 24) {
        float4 w0, w1;
        w0.x = -colv[0]; w0.y = -colv[1]; w0.z = -colv[2]; w0.w = -colv[3];
        w1.x = -colv[4]; w1.y = -colv[5]; w1.z = -colv[6]; w1.w = -colv[7];
        ((float4*)(kbase + (ln - 8) * 12))[0] = w0;
        ((float4*)(kbase + (ln - 8) * 12))[1] = w1;
      } else if (ln == 24) {
        float4 w0, w1;
        w0.x = -colv[0]; w0.y = -colv[1]; w0.z = -colv[2]; w0.w = -colv[3];
        w1.x = -colv[4]; w1.y = -colv[5]; w1.z = -colv[6]; w1.w = -colv[7];
        ((float4*)(kbase + 192))[0] = w0;
        ((float4*)(kbase + 192))[1] = w1;
      }
      const float kt0 = rdl(-colv[0], 24), kt1 = rdl(-colv[1], 24);
      const float kt2 = rdl(-colv[2], 24), kt3 = rdl(-colv[3], 24);
      const float kt4 = rdl(-colv[4], 24), kt5 = rdl(-colv[5], 24);
      const float kt6 = rdl(-colv[6], 24), kt7 = rdl(-colv[7], 24);
      if (ln < 16) {
        float a = sm[Oqh2 + ln];
        const float4 qa  = ((const float4*)(sm + OQh + ln * 28 + 16))[0];
        const float4 qb2 = ((const float4*)(sm + OQh + ln * 28 + 16))[1];
        a = fmaf(qa.x, kt0, a); a = fmaf(qa.y, kt1, a);
        a = fmaf(qa.z, kt2, a); a = fmaf(qa.w, kt3, a);
        a = fmaf(qb2.x, kt4, a); a = fmaf(qb2.y, kt5, a);
        a = fmaf(qb2.z, kt6, a); a = fmaf(qb2.w, kt7, a);
        sm[Ovls + ln] = a;
      }
    } else if (wv <= 6) {
      const int src = tid - 64;
      const int n = src / 24, d = src - n * 24;
      sm[OFT + d * 20 + n] = sm[OFb + nx * 384 + src];
    } else if (wv == 7) {
#pragma unroll
      for (int e = 0; e < 3; ++e) {
        const int src = e * 64 + ln;
        const int c = src / 24, i2 = src - c * 24;
        const float w  = sm[OWb + nx * 192 + src];
        const float sc = sm[Osv + nx * 8 + c] / sm[Ocv + nx * 8 + c];
        sm[OWT + i2 * 12 + c] = w;
        sm[OWS + i2 * 12 + c] = w * sc;
      }
    } else {
      if (ln < 8) {
        const float cc = sm[Ocv + nx * 8 + ln], ss = sm[Osv + nx * 8 + ln];
        sm[Ow2 + ln] = ss - fmaf(ss, cc, MUc) / cc;
      }
    }
    BARRIER();   // B3

    // ---- P4: V' = Qxx + Qxu*K (Schur) ----
    if (tid < 256) {
      const int n = tid >> 4, m = tid & 15;
      float acc = sm[OQh + n * 28 + m];
      const float4 qa  = ((const float4*)(sm + OQh + n * 28 + 16))[0];
      const float4 qb2 = ((const float4*)(sm + OQh + n * 28 + 16))[1];
      const float4 k0 = ((const float4*)(sm + OK2 + t * 200 + m * 12))[0];
      const float4 k1 = ((const float4*)(sm + OK2 + t * 200 + m * 12))[1];
      acc = fmaf(qa.x, k0.x, acc); acc = fmaf(qa.y, k0.y, acc);
      acc = fmaf(qa.z, k0.z, acc); acc = fmaf(qa.w, k0.w, acc);
      acc = fmaf(qb2.x, k1.x, acc); acc = fmaf(qb2.y, k1.y, acc);
      acc = fmaf(qb2.z, k1.z, acc); acc = fmaf(qb2.w, k1.w, acc);
      sm[OVp + n * 20 + m] = acc;
    }
    BARRIER();   // B4
  };

  // ---------------- prologue: stage t=63 into parity 1, init ----------------
  STAGE(Tn - 1, 1);
  if (tid < 256) {
    const int n = tid >> 4, m = tid & 15;
    sm[OVp + n * 20 + m] = VTg[(size_t)b * 256 + tid];
  } else if (tid < 272) {
    sm[Ovls + (tid - 256)] = vTg[(size_t)b * 16 + (tid - 256)];
  }
  VMW0();
  BARRIER();
  if (tid < 384) {
    const int n = tid / 24, d = tid - n * 24;
    sm[OFT + d * 20 + n] = sm[OFb + 384 + tid];
  } else {
    const int src = tid - 384;
    const int c = src / 24, i2 = src - c * 24;
    const float w  = sm[OWb + 192 + src];
    const float sc = sm[Osv + 8 + c] / sm[Ocv + 8 + c];
    sm[OWT + i2 * 12 + c] = w;
    sm[OWS + i2 * 12 + c] = w * sc;
  }
  if (tid < 8) {
    const float cc = sm[Ocv + 8 + tid], ss = sm[Osv + 8 + tid];
    sm[Ow2 + tid] = ss - fmaf(ss, cc, MUc) / cc;
  }
  BARRIER();

  // ---------------- backward scan ----------------
#pragma unroll 1
  for (int t = Tn - 1; t >= 0; --t) STEP(t);

  // ---------------- forward rollout (overlay in dead G region) ----------------
  float rfA0 = 0.f, rfA1 = 0.f, rfB0 = 0.f, rfB1 = 0.f;
  if (tid >= 384) {
    const int j = tid - 384;
#pragma unroll
    for (int slot = 0; slot < 3; ++slot) {
      sm[OFr + slot * 384 + 2 * j]     = Fg[(size_t)(slot * Bn + b) * 384 + 2 * j];
      sm[OFr + slot * 384 + 2 * j + 1] = Fg[(size_t)(slot * Bn + b) * 384 + 2 * j + 1];
    }
    rfA0 = Fg[(size_t)(3 * Bn + b) * 384 + 2 * j];
    rfA1 = Fg[(size_t)(3 * Bn + b) * 384 + 2 * j + 1];
    rfB0 = Fg[(size_t)(4 * Bn + b) * 384 + 2 * j];
    rfB1 = Fg[(size_t)(4 * Bn + b) * 384 + 2 * j + 1];
  }
  if (tid < 16) sm[Odx + tid] = x0g[(size_t)b * 16 + tid] - xnomg[(size_t)b * 16 + tid];
  BARRIER();

  if (tid >= 64 && tid < 320) {
    const int idx = tid - 64, i = idx >> 4, j = idx & 15;
    const float* fr = sm + OFr + i * 24;
    const float4 k0 = ((const float4*)(sm + OK2 + j * 12))[0];
    const float4 k1 = ((const float4*)(sm + OK2 + j * 12))[1];
    float a = fr[j];
    a = fmaf(fr[16], k0.x, a); a = fmaf(fr[17], k0.y, a);
    a = fmaf(fr[18], k0.z, a); a = fmaf(fr[19], k0.w, a);
    a = fmaf(fr[20], k1.x, a); a = fmaf(fr[21], k1.y, a);
    a = fmaf(fr[22], k1.z, a); a = fmaf(fr[23], k1.w, a);
    sm[OMs + i * 17 + j] = a;
  } else if (tid >= 320 && tid < 336) {
    const int i = tid - 320;
    const float* fr = sm + OFr + i * 24;
    float a = 0.f;
#pragma unroll
    for (int m = 0; m < 8; ++m) a = fmaf(fr[16 + m], sm[OK2 + 192 + m], a);
    sm[Obs + i] = a;
  }
  BARRIER();

#pragma unroll 1
  for (int t = 0; t < Tn; ++t) {
    const int cur = t & 1, nx2 = (t + 1) & 1;
    if (tid < 16) {
      const int i = tid;
      float a = sm[Obs + cur * 16 + i];
#pragma unroll
      for (int k2 = 0; k2 < 16; ++k2)
        a = fmaf(sm[OMs + cur * 272 + i * 17 + k2], sm[Odx + t * 16 + k2], a);
      sm[Odx + (t + 1) * 16 + i] = a;
    } else if (tid >= 64 && tid < 320) {
      if (t + 1 < Tn) {
        const int idx = tid - 64, i = idx >> 4, j = idx & 15;
        const float* fr = sm + OFr + ((t + 1) & 3) * 384 + i * 24;
        const float4 k0 = ((const float4*)(sm + OK2 + (t + 1) * 200 + j * 12))[0];
        const float4 k1 = ((const float4*)(sm + OK2 + (t + 1) * 200 + j * 12))[1];
        float a = fr[j];
        a = fmaf(fr[16], k0.x, a); a = fmaf(fr[17], k0.y, a);
        a = fmaf(fr[18], k0.z, a); a = fmaf(fr[19], k0.w, a);
        a = fmaf(fr[20], k1.x, a); a = fmaf(fr[21], k1.y, a);
        a = fmaf(fr[22], k1.z, a); a = fmaf(fr[23], k1.w, a);
        sm[OMs + nx2 * 272 + i * 17 + j] = a;
      }
    } else if (tid >= 320 && tid < 336) {
      if (t + 1 < Tn) {
        const int i = tid - 320;
        const float* fr = sm + OFr + ((t + 1) & 3) * 384 + i * 24;
        float a = 0.f;
#pragma unroll
        for (int m = 0; m < 8; ++m) a = fmaf(fr[16 + m], sm[OK2 + (t + 1) * 200 + 192 + m], a);
        sm[Obs + nx2 * 16 + i] = a;
      }
    } else if (tid >= 384) {
      const int j = tid - 384;
      if (t + 3 < Tn) {
        sm[OFr + ((t + 3) & 3) * 384 + 2 * j]     = rfA0;
        sm[OFr + ((t + 3) & 3) * 384 + 2 * j + 1] = rfA1;
      }
      rfA0 = rfB0; rfA1 = rfB1;
      if (t + 5 < Tn) {
        rfB0 = Fg[(size_t)((t + 5) * Bn + b) * 384 + 2 * j];
        rfB1 = Fg[(size_t)((t + 5) * Bn + b) * 384 + 2 * j + 1];
      }
    }
    BARRIER();
  }

  // du_t = K_t dx_t + k_t for all t in parallel
  if (tid < 512) {
    const int tt = tid >> 3, m = tid & 7;
    const float* kb = sm + OK2 + tt * 200;
    float a = kb[192 + m];
#pragma unroll
    for (int n = 0; n < 16; ++n) a = fmaf(kb[n * 12 + m], sm[Odx + tt * 16 + n], a);
    const size_t o = (size_t)(tt * Bn + b) * 8 + m;
    outg[o] = unomg[o] + a;
  }
}

extern "C" void kernel_launch(void* const* d_in, const int* in_sizes, int n_in,
                              void* d_out, int out_size, void* d_ws, size_t ws_size,
                              hipStream_t stream) {
  (void)in_sizes; (void)n_in; (void)out_size; (void)d_ws; (void)ws_size;
  const float* Qg    = (const float*)d_in[0];
  const float* qg    = (const float*)d_in[1];
  const float* Fg    = (const float*)d_in[2];
  const float* Gg    = (const float*)d_in[3];
  const float* Wg    = (const float*)d_in[4];
  const float* cg    = (const float*)d_in[5];
  const float* sg    = (const float*)d_in[6];
  const float* VTg   = (const float*)d_in[7];
  const float* vTg   = (const float*)d_in[8];
  const float* x0g   = (const float*)d_in[9];
  const float* xnomg = (const float*)d_in[10];
  const float* unomg = (const float*)d_in[11];
  float* outg = (float*)d_out;

  (void)hipFuncSetAttribute((const void*)ipddp_kernel,
                            hipFuncAttributeMaxDynamicSharedMemorySize,
                            SMEMF * 4);
  ipddp_kernel<<<dim3(Bn), dim3(576), SMEMF * 4, stream>>>(
      Qg, qg, Fg, Gg, Wg, cg, sg, VTg, vTg, x0g, xnomg, unomg, outg);
}